// Round 13
// baseline (904.939 us; speedup 1.0000x reference)
//
#include <hip/hip_runtime.h>
#include <hip/hip_bf16.h>
#include <math.h>

#define TT 512
#define NN 200
#define HH 64
#define EE 16
#define RR 10
#define MU_OFF 0
#define COV_OFF (TT*NN)      // 102400
#define HBLK (NN*NN)         // 40000 floats per t-block of cov
#define HPAD 68              // padded hist row

typedef __bf16 bf16x8 __attribute__((ext_vector_type(8)));
typedef float  f32x4  __attribute__((ext_vector_type(4)));

#define MFMA(a,b,c) __builtin_amdgcn_mfma_f32_16x16x32_bf16(a, b, c, 0, 0, 0)

__device__ __forceinline__ float sigmoidf_(float x) {
    return 1.0f / (1.0f + __expf(-x));
}
__device__ __forceinline__ float tanhf_(float x) {
    x = fminf(15.0f, fmaxf(-15.0f, x));
    float e = __expf(2.0f * x);
    return (e - 1.0f) / (e + 1.0f);
}
// unified gate activation: sigmoid(g) or tanh(g)=2*sigmoid(2g)-1
__device__ __forceinline__ float act_(float g, bool is_tanh) {
    float xx = is_tanh ? 2.0f * g : g;
    float e = __expf(-xx);
    float v = 1.0f / (1.0f + e);
    return is_tanh ? fmaf(2.0f, v, -1.0f) : v;
}

// Raw wave-counted barrier: waits LDS only (lgkmcnt), never drains vmcnt.
#define BAR() do { asm volatile("s_waitcnt lgkmcnt(0)" ::: "memory"); \
                   __builtin_amdgcn_s_barrier();                      \
                   asm volatile("" ::: "memory"); } while (0)

#define MT4(M) M(0) M(1) M(2) M(3)

// pack two float4 (8 consecutive k) into a bf16x8 fragment
#define PACK8(dst, u0, u1) \
    dst[0]=(__bf16)u0.x; dst[1]=(__bf16)u0.y; dst[2]=(__bf16)u0.z; dst[3]=(__bf16)u0.w; \
    dst[4]=(__bf16)u1.x; dst[5]=(__bf16)u1.y; dst[6]=(__bf16)u1.z; dst[7]=(__bf16)u1.w;

// load 8 consecutive floats from p, convert to a bf16x8 A-fragment
#define LDW(dst, p) { const float4* q4_ = (const float4*)(p); \
    float4 u0_ = q4_[0], u1_ = q4_[1]; PACK8(dst, u0_, u1_) }

// Pin a fragment into an AGPR tuple. Remat would need the whole global-load +
// cvt chain re-executed into AGPRs in-loop; MFMA reads A straight from AGPR.
#define PINA(v) asm volatile("" : "+a"(v))

__device__ __forceinline__ unsigned short bfbits(float a) {
    __bf16 x = (__bf16)a;
    return __builtin_bit_cast(unsigned short, x);
}

// ---------------- Kernel A: 2-layer LSTM on the MATRIX pipe, AGPR weights ---
// R11 chassis. Two fixes:
//  (1) A-fragments pinned to AGPRs ("+a") -> backend cannot re-materialize
//      them from global per tick (R11: MfmaUtil 6.7%, VALU 53% = repack code).
//  (2) h state stored as bf16 in LDS -> B-operand = 1 raw ds_read_b128
//      broadcast per K-frag (R11 re-packed B from fp32: ~20 VALU/frag/tick).
// Waves 0-3: layer0 (step t), wave w = gate w. Waves 4-7: layer1 (t-1).
// A layout: row=lane&15, k=(lane>>4)*8+j. D: col=lane&15, row=(lane>>4)*4+reg;
// B cols all identical (h broadcast) so D is col-independent; lm==0 writes ga.
__global__
__attribute__((amdgpu_flat_work_group_size(512, 512), amdgpu_waves_per_eu(2, 2)))
void lstm_kernel(
    const float* __restrict__ inputs,
    const float* __restrict__ Wih0, const float* __restrict__ Whh0,
    const float* __restrict__ bih0, const float* __restrict__ bhh0,
    const float* __restrict__ Wih1, const float* __restrict__ Whh1,
    const float* __restrict__ bih1, const float* __restrict__ bhh1,
    float* __restrict__ out)
{
    const int n    = blockIdx.x;
    const int tid  = threadIdx.x;
    const int lane = tid & 63;
    const int lm   = lane & 15;     // MFMA row/col-within-tile index
    const int kg   = lane >> 4;     // MFMA k-group (0..3)
    const int wid  = tid >> 6;      // wave 0..7

    __shared__ float xs[TT];
    __shared__ __align__(16) unsigned short h0b[HH];   // h0 as bf16
    __shared__ __align__(16) unsigned short h1b[HH];   // h1 as bf16
    __shared__ float ga0[256], ga1[256];   // ACTIVATED gates
    __shared__ float hist[64][HPAD];       // h1 history, flushed every 64 ticks

    xs[tid] = inputs[tid * NN + n];
    if (tid < HH) { h0b[tid] = 0; h1b[tid] = 0; }

    float* covbase = out + COV_OFF + n * HH;

    if (wid < 4) {
        // ================= layer-0 waves: gate = wid =================
        const int  RB   = wid * 64;
        const bool is_t = (wid == 2);
#define DECL0(mt) \
        bf16x8 aA_##mt, aB_##mt; float4 wx_##mt, bb_##mt; \
        { const float* pw_ = Whh0 + (size_t)(RB + mt*16 + lm) * HH + kg * 8; \
          LDW(aA_##mt, pw_); LDW(aB_##mt, pw_ + 32); \
          PINA(aA_##mt); PINA(aB_##mt); \
          const int er_ = RB + mt*16 + kg*4; \
          wx_##mt = *(const float4*)(Wih0 + er_); \
          float4 b1_ = *(const float4*)(bih0 + er_); \
          float4 b2_ = *(const float4*)(bhh0 + er_); \
          bb_##mt.x = b1_.x + b2_.x; bb_##mt.y = b1_.y + b2_.y; \
          bb_##mt.z = b1_.z + b2_.z; bb_##mt.w = b1_.w + b2_.w; }
        MT4(DECL0)
        float c0 = 0.0f;            // live in lanes of wave 0 (tid<64)

        BAR();  // init

        for (int t = 0; t <= TT; ++t) {
            if (t < TT) {
                const float x = xs[t];
                // B-frags: raw bf16 h0 broadcast (addr depends only on kg)
                bf16x8 B0 = *(const bf16x8*)(h0b + kg * 8);
                bf16x8 B1 = *(const bf16x8*)(h0b + 32 + kg * 8);
#define MM0(mt) { f32x4 d_ = {0.f, 0.f, 0.f, 0.f}; \
                d_ = MFMA(aA_##mt, B0, d_); \
                d_ = MFMA(aB_##mt, B1, d_); \
                float gx_ = act_(d_[0] + fmaf(wx_##mt.x, x, bb_##mt.x), is_t); \
                float gy_ = act_(d_[1] + fmaf(wx_##mt.y, x, bb_##mt.y), is_t); \
                float gz_ = act_(d_[2] + fmaf(wx_##mt.z, x, bb_##mt.z), is_t); \
                float gw_ = act_(d_[3] + fmaf(wx_##mt.w, x, bb_##mt.w), is_t); \
                if (lm == 0) { \
                    float4 g_; g_.x = gx_; g_.y = gy_; g_.z = gz_; g_.w = gw_; \
                    *(float4*)(ga0 + RB + mt*16 + kg*4) = g_; } }
                MT4(MM0)
            }
            BAR();
            if (t < TT && tid < HH) {
                float ia = ga0[tid], fa = ga0[tid + 64];
                float gg = ga0[tid + 128], oa = ga0[tid + 192];
                c0 = fmaf(fa, c0, ia * gg);
                h0b[tid] = bfbits(oa * tanhf_(c0));
            }
            BAR();
            if ((t & 63) == 0 && t > 0) {   // flush steps t-64..t-1
                const int s  = tid >> 3;
                const int cc = (tid & 7) * 8;
                float4 v0 = *(const float4*)&hist[s][cc];
                float4 v1 = *(const float4*)&hist[s][cc + 4];
                float* dst = covbase + (size_t)(t - 64 + s) * HBLK + cc;
                ((float4*)dst)[0] = v0;
                ((float4*)dst)[1] = v1;
            }
        }
    } else {
        // ================= layer-1 waves: gate = wid-4, step t-1 =======
        const int  RB   = (wid - 4) * 64;
        const bool is_t = (wid == 6);
#define DECL1(mt) \
        bf16x8 aI0_##mt, aI1_##mt, aH0_##mt, aH1_##mt; float4 bb_##mt; \
        { const size_t ro_ = (size_t)(RB + mt*16 + lm) * HH + kg * 8; \
          LDW(aI0_##mt, Wih1 + ro_); LDW(aI1_##mt, Wih1 + ro_ + 32); \
          LDW(aH0_##mt, Whh1 + ro_); LDW(aH1_##mt, Whh1 + ro_ + 32); \
          PINA(aI0_##mt); PINA(aI1_##mt); PINA(aH0_##mt); PINA(aH1_##mt); \
          const int er_ = RB + mt*16 + kg*4; \
          float4 b1_ = *(const float4*)(bih1 + er_); \
          float4 b2_ = *(const float4*)(bhh1 + er_); \
          bb_##mt.x = b1_.x + b2_.x; bb_##mt.y = b1_.y + b2_.y; \
          bb_##mt.z = b1_.z + b2_.z; bb_##mt.w = b1_.w + b2_.w; }
        MT4(DECL1)
        float c1 = 0.0f;            // live in lanes of wave 4 (tid 256..319)

        BAR();  // init

        for (int t = 0; t <= TT; ++t) {
            if (t >= 1) {
                bf16x8 B0 = *(const bf16x8*)(h0b + kg * 8);
                bf16x8 B1 = *(const bf16x8*)(h0b + 32 + kg * 8);
                bf16x8 B2 = *(const bf16x8*)(h1b + kg * 8);
                bf16x8 B3 = *(const bf16x8*)(h1b + 32 + kg * 8);
#define MM1(mt) { f32x4 d_ = {0.f, 0.f, 0.f, 0.f}; \
                d_ = MFMA(aI0_##mt, B0, d_); \
                d_ = MFMA(aI1_##mt, B1, d_); \
                d_ = MFMA(aH0_##mt, B2, d_); \
                d_ = MFMA(aH1_##mt, B3, d_); \
                float gx_ = act_(d_[0] + bb_##mt.x, is_t); \
                float gy_ = act_(d_[1] + bb_##mt.y, is_t); \
                float gz_ = act_(d_[2] + bb_##mt.z, is_t); \
                float gw_ = act_(d_[3] + bb_##mt.w, is_t); \
                if (lm == 0) { \
                    float4 g_; g_.x = gx_; g_.y = gy_; g_.z = gz_; g_.w = gw_; \
                    *(float4*)(ga1 + RB + mt*16 + kg*4) = g_; } }
                MT4(MM1)
            }
            BAR();
            if (t >= 1 && tid >= 256 && tid < 256 + HH) {
                const int j = tid - 256;
                float ia = ga1[j], fa = ga1[j + 64];
                float gg = ga1[j + 128], oa = ga1[j + 192];
                c1 = fmaf(fa, c1, ia * gg);
                float h1 = oa * tanhf_(c1);
                h1b[j] = bfbits(h1);
                hist[(t - 1) & 63][j] = h1;
            }
            BAR();
            if ((t & 63) == 0 && t > 0) {   // flush steps t-64..t-1
                const int s  = tid >> 3;
                const int cc = (tid & 7) * 8;
                float4 v0 = *(const float4*)&hist[s][cc];
                float4 v1 = *(const float4*)&hist[s][cc + 4];
                float* dst = covbase + (size_t)(t - 64 + s) * HBLK + cc;
                ((float4*)dst)[0] = v0;
                ((float4*)dst)[1] = v1;
            }
        }
    }
}

// ---------------- Kernel B: heads + covariance, one workgroup per t ----------
__global__ __launch_bounds__(256) void head_kernel(
    const float* __restrict__ embW, const int* __restrict__ indices,
    const float* __restrict__ Wm, const float* __restrict__ bm,
    const float* __restrict__ Wv, const float* __restrict__ bv,
    const float* __restrict__ Wd, const float* __restrict__ bd,
    float* __restrict__ out)
{
    const int t = blockIdx.x;
    const int tid = threadIdx.x;

    __shared__ float hs[NN * HH];          // 12800
    __shared__ float embs[NN * EE];        // 3200
    __shared__ float Wvs[(HH + EE) * RR];  // 800
    __shared__ float Wms[HH + EE];
    __shared__ float Wds[HH + EE];
    __shared__ float Vs[NN * (RR + 1)];    // stride 11 to dodge bank conflicts
    __shared__ float dsh[NN];
    __shared__ float bvs[RR];

    const float* hsrc = out + COV_OFF + (size_t)t * HBLK;
    for (int i = tid; i < (NN * HH) / 4; i += 256)
        ((float4*)hs)[i] = ((const float4*)hsrc)[i];
    for (int i = tid; i < NN * EE; i += 256) {
        int n = i >> 4, e = i & 15;
        embs[i] = embW[indices[n] * EE + e];
    }
    for (int i = tid; i < (HH + EE) * RR; i += 256) Wvs[i] = Wv[i];
    if (tid < HH + EE) { Wms[tid] = Wm[tid]; Wds[tid] = Wd[tid]; }
    if (tid < RR) bvs[tid] = bv[tid];
    __syncthreads();

    // V = y @ Wv + bv
    for (int p = tid; p < NN * RR; p += 256) {
        int n = p / RR, r = p - n * RR;
        const float* hn = hs + n * HH;
        const float* en = embs + n * EE;
        float acc = bvs[r];
#pragma unroll 8
        for (int k = 0; k < HH; ++k) acc = fmaf(hn[k], Wvs[k * RR + r], acc);
#pragma unroll
        for (int k = 0; k < EE; ++k) acc = fmaf(en[k], Wvs[(HH + k) * RR + r], acc);
        Vs[n * (RR + 1) + r] = acc;
    }
    // mu and d
    const float bmv = bm[0], bdv = bd[0];
    for (int n = tid; n < NN; n += 256) {
        const float* hn = hs + n * HH;
        const float* en = embs + n * EE;
        float am = bmv, ad = bdv;
#pragma unroll 8
        for (int k = 0; k < HH; ++k) {
            float h = hn[k];
            am = fmaf(h, Wms[k], am);
            ad = fmaf(h, Wds[k], ad);
        }
#pragma unroll
        for (int k = 0; k < EE; ++k) {
            float e = en[k];
            am = fmaf(e, Wms[HH + k], am);
            ad = fmaf(e, Wds[HH + k], ad);
        }
        out[MU_OFF + t * NN + n] = am;
        dsh[n] = (ad > 20.0f) ? ad : log1pf(__expf(ad));  // softplus
    }
    __syncthreads();

    // cov[t] = V V^T + diag(d)  — overwrites the whole block (incl. stashed h)
    float* covp = out + COV_OFF + (size_t)t * HBLK;
    for (int p = tid; p < NN * NN; p += 256) {
        int n = p / NN, m = p - n * NN;
        const float* vn = Vs + n * (RR + 1);
        const float* vm = Vs + m * (RR + 1);
        float acc = (n == m) ? dsh[n] : 0.0f;
#pragma unroll
        for (int r = 0; r < RR; ++r) acc = fmaf(vn[r], vm[r], acc);
        covp[p] = acc;
    }
}

extern "C" void kernel_launch(void* const* d_in, const int* in_sizes, int n_in,
                              void* d_out, int out_size, void* d_ws, size_t ws_size,
                              hipStream_t stream) {
    const float* inputs  = (const float*)d_in[0];
    const int*   indices = (const int*)d_in[1];
    const float* embW    = (const float*)d_in[2];
    const float* Wih0    = (const float*)d_in[3];
    const float* Whh0    = (const float*)d_in[4];
    const float* bih0    = (const float*)d_in[5];
    const float* bhh0    = (const float*)d_in[6];
    const float* Wih1    = (const float*)d_in[7];
    const float* Whh1    = (const float*)d_in[8];
    const float* bih1    = (const float*)d_in[9];
    const float* bhh1    = (const float*)d_in[10];
    const float* Wm      = (const float*)d_in[11];
    const float* bm      = (const float*)d_in[12];
    const float* Wv      = (const float*)d_in[13];
    const float* bv      = (const float*)d_in[14];
    const float* Wd      = (const float*)d_in[15];
    const float* bd      = (const float*)d_in[16];
    float* out = (float*)d_out;

    lstm_kernel<<<NN, 512, 0, stream>>>(inputs, Wih0, Whh0, bih0, bhh0,
                                        Wih1, Whh1, bih1, bhh1, out);
    head_kernel<<<TT, 256, 0, stream>>>(embW, indices, Wm, bm, Wv, bv, Wd, bd, out);
}

// Round 14
// 398.119 us; speedup vs baseline: 2.2730x; 2.2730x over previous
//
#include <hip/hip_runtime.h>
#include <hip/hip_bf16.h>
#include <math.h>

#define TT 512
#define NN 200
#define HH 64
#define EE 16
#define RR 10
#define MU_OFF 0
#define COV_OFF (TT*NN)      // 102400
#define HBLK (NN*NN)         // 40000 floats per t-block of cov
#define HPAD 68              // padded hist row

__device__ __forceinline__ float sigmoidf_(float x) {
    return 1.0f / (1.0f + __expf(-x));
}
__device__ __forceinline__ float tanhf_(float x) {
    x = fminf(15.0f, fmaxf(-15.0f, x));
    float e = __expf(2.0f * x);
    return (e - 1.0f) / (e + 1.0f);
}
// unified gate activation: sigmoid(g) or tanh(g)=2*sigmoid(2g)-1
__device__ __forceinline__ float act_(float g, bool is_tanh) {
    float xx = is_tanh ? 2.0f * g : g;
    float e = __expf(-xx);
    float v = 1.0f / (1.0f + e);
    return is_tanh ? fmaf(2.0f, v, -1.0f) : v;
}

// quad_perm DPP xor-swaps (VALU pipe, not LDS pipe)
__device__ __forceinline__ float dppxor1(float v) {   // lanes [1,0,3,2]
    return __int_as_float(__builtin_amdgcn_mov_dpp(__float_as_int(v), 0xB1, 0xf, 0xf, true));
}
__device__ __forceinline__ float dppxor2(float v) {   // lanes [2,3,0,1]
    return __int_as_float(__builtin_amdgcn_mov_dpp(__float_as_int(v), 0x4E, 0xf, 0xf, true));
}

// v_dot2_f32_bf16: acc += w.bf16[0]*h.bf16[0] + w.bf16[1]*h.bf16[1]
// (validated end-to-end in R12: passed, absmax 0.0625)
__device__ __forceinline__ void dot2(float& acc, unsigned w, unsigned h) {
    asm("v_dot2_f32_bf16 %0, %1, %2, %0" : "+v"(acc) : "v"(w), "v"(h));
}

// pack two floats into one dword of 2 bf16 (RNE)
__device__ __forceinline__ unsigned pk2(float a, float b) {
    __bf16 x = (__bf16)a, y = (__bf16)b;
    unsigned short ux = __builtin_bit_cast(unsigned short, x);
    unsigned short uy = __builtin_bit_cast(unsigned short, y);
    return (unsigned)ux | ((unsigned)uy << 16);
}
__device__ __forceinline__ unsigned short bfbits(float a) {
    __bf16 x = (__bf16)a;
    return __builtin_bit_cast(unsigned short, x);
}

// Raw wave-counted barrier: waits LDS only (lgkmcnt), never drains vmcnt.
#define BAR() do { asm volatile("s_waitcnt lgkmcnt(0)" ::: "memory"); \
                   __builtin_amdgcn_s_barrier();                      \
                   asm volatile("" ::: "memory"); } while (0)

#define PINU4(v) asm volatile("" : "+v"(v.x), "+v"(v.y), "+v"(v.z), "+v"(v.w))
#define RM4(M) M(0) M(1) M(2) M(3)

// pack 16 consecutive fp32 weights at p into two uint4 of bf16 pairs
#define PKW(d0, d1, p) { const float* s_ = (p); \
    d0.x = pk2(s_[0], s_[1]);   d0.y = pk2(s_[2], s_[3]); \
    d0.z = pk2(s_[4], s_[5]);   d0.w = pk2(s_[6], s_[7]); \
    d1.x = pk2(s_[8], s_[9]);   d1.y = pk2(s_[10], s_[11]); \
    d1.z = pk2(s_[12], s_[13]); d1.w = pk2(s_[14], s_[15]); }

// ---------------- Kernel A: 2-layer LSTM, bf16-packed register weights ------
// R7 chassis (best so far). Session model: the allocator budgets ~88 VGPRs
// for the whole kernel and spills any branch above it; spilled weights then
// re-stream every tick (the 1650cy plateau). Fix: bf16-pack the weights so
// branch A holds 32 dwords and branch B 64 dwords -> both (nearly) fit the
// budget; v_dot2_f32_bf16 also halves FMA issue. h state is bf16 in LDS so
// the per-tick operand read is 2 raw ds_read_b128 (no repack VALU).
// Waves 0-3: layer0 (step t). Waves 4-7: layer1 (step t-1). 2 barriers/tick.
__global__
__attribute__((amdgpu_flat_work_group_size(512, 512), amdgpu_waves_per_eu(2, 2)))
void lstm_kernel(
    const float* __restrict__ inputs,
    const float* __restrict__ Wih0, const float* __restrict__ Whh0,
    const float* __restrict__ bih0, const float* __restrict__ bhh0,
    const float* __restrict__ Wih1, const float* __restrict__ Whh1,
    const float* __restrict__ bih1, const float* __restrict__ bhh1,
    float* __restrict__ out)
{
    const int n   = blockIdx.x;
    const int tid = threadIdx.x;

    __shared__ float xs[TT];
    __shared__ __align__(16) unsigned short h0b[HH];   // h0 as bf16
    __shared__ __align__(16) unsigned short h1b[HH];   // h1 as bf16
    __shared__ float ga0[256], ga1[256];     // activated gates (fp32)
    __shared__ float hist[64][HPAD];         // h1 history (fp32)

    xs[tid] = inputs[tid * NN + n];
    if (tid < HH) { h0b[tid] = 0; h1b[tid] = 0; }

    float* covbase = out + COV_OFF + n * HH;

    if (tid < 256) {
        // ================= layer-0 branch (waves 0-3) =================
        const int b4 = tid & ~3;        // first of this thread's 4 rows
        const int qr = tid & 3;         // k-quarter (16 values)
#define DECLA(m) \
        uint4 wa##m##_0, wa##m##_1; \
        PKW(wa##m##_0, wa##m##_1, Whh0 + (b4 + m) * HH + qr * 16); \
        PINU4(wa##m##_0); PINU4(wa##m##_1);
        RM4(DECLA)
        const float wx = Wih0[tid];
        const float b0 = bih0[tid] + bhh0[tid];
        const bool is_t = ((tid >> 6) == 2);
        float c0 = 0.0f;

        BAR();  // init

        for (int t = 0; t <= TT; ++t) {
            if (t < TT) {
                const float x = xs[t];
                const uint4* hp = (const uint4*)(h0b + qr * 16);  // qr*32B
                uint4 ha = hp[0], hb = hp[1];
                float acc0, acc1, acc2, acc3;
#define MVA(m) { \
                float a_ = 0.0f; \
                dot2(a_, wa##m##_0.x, ha.x); dot2(a_, wa##m##_0.y, ha.y); \
                dot2(a_, wa##m##_0.z, ha.z); dot2(a_, wa##m##_0.w, ha.w); \
                dot2(a_, wa##m##_1.x, hb.x); dot2(a_, wa##m##_1.y, hb.y); \
                dot2(a_, wa##m##_1.z, hb.z); dot2(a_, wa##m##_1.w, hb.w); \
                acc##m = a_; }
                RM4(MVA)
                acc0 += dppxor1(acc0); acc0 += dppxor2(acc0);
                acc1 += dppxor1(acc1); acc1 += dppxor2(acc1);
                acc2 += dppxor1(acc2); acc2 += dppxor2(acc2);
                acc3 += dppxor1(acc3); acc3 += dppxor2(acc3);
                float g = (qr == 0) ? acc0 : (qr == 1) ? acc1 : (qr == 2) ? acc2 : acc3;
                g += fmaf(wx, x, b0);           // own row == tid
                ga0[tid] = act_(g, is_t);
            }
            BAR();
            if (t < TT && tid < HH) {
                float ia = ga0[tid], fa = ga0[tid + 64];
                float gg = ga0[tid + 128], oa = ga0[tid + 192];
                c0 = fmaf(fa, c0, ia * gg);
                h0b[tid] = bfbits(oa * tanhf_(c0));
            }
            BAR();
            if ((t & 63) == 0 && t > 0) {   // flush steps t-64..t-1 (A half)
                const int s  = tid >> 3;
                const int cc = (tid & 7) * 8;
                float4 v0 = *(const float4*)&hist[s][cc];
                float4 v1 = *(const float4*)&hist[s][cc + 4];
                float* dst = covbase + (size_t)(t - 64 + s) * HBLK + cc;
                ((float4*)dst)[0] = v0;
                ((float4*)dst)[1] = v1;
            }
        }
    } else {
        // ================= layer-1 branch (waves 4-7), step t-1 ========
        const int r  = tid - 256;
        const int b4 = r & ~3;
        const int qr = r & 3;
#define DECLB(m) \
        uint4 wi##m##_0, wi##m##_1, wh##m##_0, wh##m##_1; \
        PKW(wi##m##_0, wi##m##_1, Wih1 + (b4 + m) * HH + qr * 16); \
        PKW(wh##m##_0, wh##m##_1, Whh1 + (b4 + m) * HH + qr * 16); \
        PINU4(wi##m##_0); PINU4(wi##m##_1); PINU4(wh##m##_0); PINU4(wh##m##_1);
        RM4(DECLB)
        const float b1 = bih1[r] + bhh1[r];
        const bool is_t = ((r >> 6) == 2);
        float c1 = 0.0f;

        BAR();  // init

        for (int t = 0; t <= TT; ++t) {
            if (t >= 1) {
                const uint4* hp0 = (const uint4*)(h0b + qr * 16);
                const uint4* hp1 = (const uint4*)(h1b + qr * 16);
                uint4 ha0 = hp0[0], ha1 = hp0[1];
                uint4 hb0 = hp1[0], hb1 = hp1[1];
                float acc0, acc1, acc2, acc3;
#define MVB(m) { \
                float a_ = 0.0f, s_ = 0.0f; \
                dot2(a_, wi##m##_0.x, ha0.x); dot2(a_, wi##m##_0.y, ha0.y); \
                dot2(a_, wi##m##_0.z, ha0.z); dot2(a_, wi##m##_0.w, ha0.w); \
                dot2(a_, wi##m##_1.x, ha1.x); dot2(a_, wi##m##_1.y, ha1.y); \
                dot2(a_, wi##m##_1.z, ha1.z); dot2(a_, wi##m##_1.w, ha1.w); \
                dot2(s_, wh##m##_0.x, hb0.x); dot2(s_, wh##m##_0.y, hb0.y); \
                dot2(s_, wh##m##_0.z, hb0.z); dot2(s_, wh##m##_0.w, hb0.w); \
                dot2(s_, wh##m##_1.x, hb1.x); dot2(s_, wh##m##_1.y, hb1.y); \
                dot2(s_, wh##m##_1.z, hb1.z); dot2(s_, wh##m##_1.w, hb1.w); \
                acc##m = a_ + s_; }
                RM4(MVB)
                acc0 += dppxor1(acc0); acc0 += dppxor2(acc0);
                acc1 += dppxor1(acc1); acc1 += dppxor2(acc1);
                acc2 += dppxor1(acc2); acc2 += dppxor2(acc2);
                acc3 += dppxor1(acc3); acc3 += dppxor2(acc3);
                float g = (qr == 0) ? acc0 : (qr == 1) ? acc1 : (qr == 2) ? acc2 : acc3;
                g += b1;                        // own row == r
                ga1[r] = act_(g, is_t);
            }
            BAR();
            if (t >= 1 && tid < 256 + HH) {     // wave 4, lanes 0-63
                const int j = tid - 256;
                float ia = ga1[j], fa = ga1[j + 64];
                float gg = ga1[j + 128], oa = ga1[j + 192];
                c1 = fmaf(fa, c1, ia * gg);
                float h1 = oa * tanhf_(c1);
                h1b[j] = bfbits(h1);
                hist[(t - 1) & 63][j] = h1;
            }
            BAR();
            if ((t & 63) == 0 && t > 0) {   // flush steps t-64..t-1 (B half)
                const int s  = tid >> 3;
                const int cc = (tid & 7) * 8;
                float4 v0 = *(const float4*)&hist[s][cc];
                float4 v1 = *(const float4*)&hist[s][cc + 4];
                float* dst = covbase + (size_t)(t - 64 + s) * HBLK + cc;
                ((float4*)dst)[0] = v0;
                ((float4*)dst)[1] = v1;
            }
        }
    }
}

// ---------------- Kernel B: heads + covariance, one workgroup per t ----------
__global__ __launch_bounds__(256) void head_kernel(
    const float* __restrict__ embW, const int* __restrict__ indices,
    const float* __restrict__ Wm, const float* __restrict__ bm,
    const float* __restrict__ Wv, const float* __restrict__ bv,
    const float* __restrict__ Wd, const float* __restrict__ bd,
    float* __restrict__ out)
{
    const int t = blockIdx.x;
    const int tid = threadIdx.x;

    __shared__ float hs[NN * HH];          // 12800
    __shared__ float embs[NN * EE];        // 3200
    __shared__ float Wvs[(HH + EE) * RR];  // 800
    __shared__ float Wms[HH + EE];
    __shared__ float Wds[HH + EE];
    __shared__ float Vs[NN * (RR + 1)];    // stride 11 to dodge bank conflicts
    __shared__ float dsh[NN];
    __shared__ float bvs[RR];

    const float* hsrc = out + COV_OFF + (size_t)t * HBLK;
    for (int i = tid; i < (NN * HH) / 4; i += 256)
        ((float4*)hs)[i] = ((const float4*)hsrc)[i];
    for (int i = tid; i < NN * EE; i += 256) {
        int n = i >> 4, e = i & 15;
        embs[i] = embW[indices[n] * EE + e];
    }
    for (int i = tid; i < (HH + EE) * RR; i += 256) Wvs[i] = Wv[i];
    if (tid < HH + EE) { Wms[tid] = Wm[tid]; Wds[tid] = Wd[tid]; }
    if (tid < RR) bvs[tid] = bv[tid];
    __syncthreads();

    // V = y @ Wv + bv
    for (int p = tid; p < NN * RR; p += 256) {
        int n = p / RR, r = p - n * RR;
        const float* hn = hs + n * HH;
        const float* en = embs + n * EE;
        float acc = bvs[r];
#pragma unroll 8
        for (int k = 0; k < HH; ++k) acc = fmaf(hn[k], Wvs[k * RR + r], acc);
#pragma unroll
        for (int k = 0; k < EE; ++k) acc = fmaf(en[k], Wvs[(HH + k) * RR + r], acc);
        Vs[n * (RR + 1) + r] = acc;
    }
    // mu and d
    const float bmv = bm[0], bdv = bd[0];
    for (int n = tid; n < NN; n += 256) {
        const float* hn = hs + n * HH;
        const float* en = embs + n * EE;
        float am = bmv, ad = bdv;
#pragma unroll 8
        for (int k = 0; k < HH; ++k) {
            float h = hn[k];
            am = fmaf(h, Wms[k], am);
            ad = fmaf(h, Wds[k], ad);
        }
#pragma unroll
        for (int k = 0; k < EE; ++k) {
            float e = en[k];
            am = fmaf(e, Wms[HH + k], am);
            ad = fmaf(e, Wds[HH + k], ad);
        }
        out[MU_OFF + t * NN + n] = am;
        dsh[n] = (ad > 20.0f) ? ad : log1pf(__expf(ad));  // softplus
    }
    __syncthreads();

    // cov[t] = V V^T + diag(d)  — overwrites the whole block (incl. stashed h)
    float* covp = out + COV_OFF + (size_t)t * HBLK;
    for (int p = tid; p < NN * NN; p += 256) {
        int n = p / NN, m = p - n * NN;
        const float* vn = Vs + n * (RR + 1);
        const float* vm = Vs + m * (RR + 1);
        float acc = (n == m) ? dsh[n] : 0.0f;
#pragma unroll
        for (int r = 0; r < RR; ++r) acc = fmaf(vn[r], vm[r], acc);
        covp[p] = acc;
    }
}

extern "C" void kernel_launch(void* const* d_in, const int* in_sizes, int n_in,
                              void* d_out, int out_size, void* d_ws, size_t ws_size,
                              hipStream_t stream) {
    const float* inputs  = (const float*)d_in[0];
    const int*   indices = (const int*)d_in[1];
    const float* embW    = (const float*)d_in[2];
    const float* Wih0    = (const float*)d_in[3];
    const float* Whh0    = (const float*)d_in[4];
    const float* bih0    = (const float*)d_in[5];
    const float* bhh0    = (const float*)d_in[6];
    const float* Wih1    = (const float*)d_in[7];
    const float* Whh1    = (const float*)d_in[8];
    const float* bih1    = (const float*)d_in[9];
    const float* bhh1    = (const float*)d_in[10];
    const float* Wm      = (const float*)d_in[11];
    const float* bm      = (const float*)d_in[12];
    const float* Wv      = (const float*)d_in[13];
    const float* bv      = (const float*)d_in[14];
    const float* Wd      = (const float*)d_in[15];
    const float* bd      = (const float*)d_in[16];
    float* out = (float*)d_out;

    lstm_kernel<<<NN, 512, 0, stream>>>(inputs, Wih0, Whh0, bih0, bhh0,
                                        Wih1, Whh1, bih1, bhh1, out);
    head_kernel<<<TT, 256, 0, stream>>>(embW, indices, Wm, bm, Wv, bv, Wd, bd, out);
}